// Round 7
// baseline (466.553 us; speedup 1.0000x reference)
//
#include <hip/hip_runtime.h>
#include <math.h>

#define NB 4
#define NP 8192
#define KK 16
#define QPB 64
#define NWAVE 8
#define NCHUNK 16
#define CHUNK (NP / NCHUNK)   // 512
#define NPTS (NB * NP)

// comparator macros (exact: min/max introduce no rounding)
#define CSWAP_DESC(a, b) { float _lo = fminf(a, b); float _hi = fmaxf(a, b); a = _hi; b = _lo; }
#define CSWAP_ASC(a, b)  { float _lo = fminf(a, b); float _hi = fmaxf(a, b); a = _lo; b = _hi; }

// reference-rounded |p|^2 : (xx+yy)+zz
__device__ __forceinline__ float ref_sq(float x, float y, float z) {
  return __fadd_rn(__fadd_rn(__fmul_rn(x, x), __fmul_rn(y, y)), __fmul_rn(z, z));
}

// reference-rounded d2 = (sqq + sqc) - 2*dot, dot = (xx+yy)+zz
__device__ __forceinline__ float ref_d2q(float qx, float qy, float qz, float sqq,
                                         float4 c) {
  float dot = __fadd_rn(__fadd_rn(__fmul_rn(qx, c.x), __fmul_rn(qy, c.y)),
                        __fmul_rn(qz, c.z));
  float s = __fadd_rn(sqq, c.w);
  return __fmaf_rn(-2.0f, dot, s);   // 2*dot exact => identical to fl(s - 2*dot)
}

__global__ void prep_kernel(const float* __restrict__ x,
                            float4* __restrict__ cand) {
  int i = blockIdx.x * 256 + threadIdx.x;
  if (i < NPTS) {
    float px = x[3 * i + 0], py = x[3 * i + 1], pz = x[3 * i + 2];
    cand[i] = make_float4(px, py, pz, ref_sq(px, py, pz));
  }
}

// ---------------- k1: per-chunk exact top-16, lists to global ----------------
// grid: NB * 128 groups * 2 halves = 1024 blocks, 512 threads (8 waves)
// wave w of block-half scans chunk (half*8 + w) of 512 candidates.
// Phase-1/2 inner code is VERBATIM the R4-passing kernel (8-wide, inline net).
__global__ __launch_bounds__(512) void knn_lists_kernel(
    const float4* __restrict__ cand, unsigned short* __restrict__ lists) {
  const int tid   = threadIdx.x;
  const int lane  = tid & 63;
  const int w     = __builtin_amdgcn_readfirstlane(tid >> 6);
  const int bid   = blockIdx.x;
  const int batch = bid >> 8;              // 256 blocks per batch
  const int rem   = bid & 255;
  const int group = rem >> 1;
  const int half  = rem & 1;
  const int qbase = group * QPB;
  const int chunkid = half * NWAVE + w;    // 0..15
  const int j0 = chunkid * CHUNK;

  const float4* __restrict__ Cb = cand + (size_t)batch * NP;

  // query point (per-lane)
  const float4 q = Cb[qbase + lane];
  const float qx = q.x, qy = q.y, qz = q.z, sqq = q.w;

  // ---- phase 1: exact top-16 DISTANCES over this wave's 512-candidate chunk
  float bd[KK];
#pragma unroll
  for (int t = 0; t < KK; ++t) bd[t] = 3.4e38f;

  for (int jj = 0; jj < CHUNK; jj += 8) {
    const float4* xp = Cb + (j0 + jj);          // wave-uniform address
    float4 c[8];
#pragma unroll
    for (int u = 0; u < 8; ++u) c[u] = xp[u];

    float d[8];
#pragma unroll
    for (int u = 0; u < 8; ++u) d[u] = ref_d2q(qx, qy, qz, sqq, c[u]);

    // Batcher odd-even mergesort-8, DESCENDING (19 comparators)
    CSWAP_DESC(d[0], d[1]) CSWAP_DESC(d[2], d[3]) CSWAP_DESC(d[4], d[5]) CSWAP_DESC(d[6], d[7])
    CSWAP_DESC(d[0], d[2]) CSWAP_DESC(d[1], d[3]) CSWAP_DESC(d[4], d[6]) CSWAP_DESC(d[5], d[7])
    CSWAP_DESC(d[1], d[2]) CSWAP_DESC(d[5], d[6])
    CSWAP_DESC(d[0], d[4]) CSWAP_DESC(d[1], d[5]) CSWAP_DESC(d[2], d[6]) CSWAP_DESC(d[3], d[7])
    CSWAP_DESC(d[2], d[4]) CSWAP_DESC(d[3], d[5])
    CSWAP_DESC(d[1], d[2]) CSWAP_DESC(d[3], d[4]) CSWAP_DESC(d[5], d[6])

    // [bd_asc(16), +inf x8, d_desc(8)] is bitonic; halver keeps 16 smallest
#pragma unroll
    for (int i = 0; i < 8; ++i) bd[8 + i] = fminf(bd[8 + i], d[i]);

    // bitonic merge-16 ascending cleanup (32 comparators)
#pragma unroll
    for (int i = 0; i < 8; ++i)  CSWAP_ASC(bd[i], bd[i + 8])
#pragma unroll
    for (int i = 0; i < 4; ++i)  CSWAP_ASC(bd[i], bd[i + 4])
#pragma unroll
    for (int i = 8; i < 12; ++i) CSWAP_ASC(bd[i], bd[i + 4])
#pragma unroll
    for (int g = 0; g < 4; ++g) {
      CSWAP_ASC(bd[4 * g + 0], bd[4 * g + 2]) CSWAP_ASC(bd[4 * g + 1], bd[4 * g + 3])
      CSWAP_ASC(bd[4 * g + 0], bd[4 * g + 1]) CSWAP_ASC(bd[4 * g + 2], bd[4 * g + 3])
    }
  }

  const float T = bd[KK - 1];   // exact 16th-smallest (ref-rounded) in chunk

  // ---- phase 2: recover indices (ascending j => matches stable top_k ties)
  unsigned short* Lrow =
      lists + (((size_t)batch * NP + qbase + lane) * NCHUNK + chunkid) * KK;
  int cnt = 0;
  for (int jj = 0; jj < CHUNK; jj += 8) {
    const float4* xp = Cb + (j0 + jj);
    float4 c[8];
#pragma unroll
    for (int u = 0; u < 8; ++u) c[u] = xp[u];
#pragma unroll
    for (int u = 0; u < 8; ++u) {
      float d = ref_d2q(qx, qy, qz, sqq, c[u]);
      if (d <= T && cnt < KK) {
        Lrow[cnt] = (unsigned short)(j0 + jj + u);
        cnt++;
      }
    }
  }
}

// ---------------- k2: merge 16 lists + covariance + eigen -------------------
// grid: 32768/64 = 512 blocks, 64 threads; one query per lane.
__global__ __launch_bounds__(64) void merge_eigen_kernel(
    const float4* __restrict__ cand, const unsigned short* __restrict__ lists,
    float* __restrict__ out) {
  const int g = blockIdx.x * 64 + threadIdx.x;   // global query id
  const int batch = g >> 13;                     // / NP
  const float4* __restrict__ Cb = cand + (size_t)batch * NP;

  const float4 qq = cand[g];
  const float q2x = qq.x, q2y = qq.y, q2z = qq.z, sq2 = qq.w;

  float md[KK]; int mj[KK];
#pragma unroll
  for (int t = 0; t < KK; ++t) { md[t] = 3.4e38f; mj[t] = 0; }

  const unsigned int* Lq = (const unsigned int*)(lists + (size_t)g * NCHUNK * KK);
  for (int cch = 0; cch < NCHUNK; ++cch) {
    const unsigned int* rowp = Lq + cch * (KK / 2);
#pragma unroll
    for (int sp = 0; sp < KK / 2; ++sp) {
      unsigned int pk = rowp[sp];
#pragma unroll
      for (int half = 0; half < 2; ++half) {
        int j = (half == 0) ? (int)(pk & 0xFFFFu) : (int)(pk >> 16);
        float d = ref_d2q(q2x, q2y, q2z, sq2, Cb[j]);
        if (d < md[KK - 1]) {
          bool c0 = d < md[0];
#pragma unroll
          for (int t = KK - 1; t >= 1; --t) {
            bool cl = d < md[t];
            bool cp = d < md[t - 1];
            float nv = fmaxf(md[t - 1], fminf(md[t], d));
            mj[t] = cl ? (cp ? mj[t - 1] : j) : mj[t];
            md[t] = nv;
          }
          mj[0] = c0 ? j : mj[0];
          md[0] = fminf(md[0], d);
        }
      }
    }
  }

  // mean of the 16 neighbors (sequential fp32, then exact /16)
  float sx = 0.f, sy = 0.f, sz = 0.f;
#pragma unroll
  for (int s = 0; s < KK; ++s) {
    float4 pp = Cb[mj[s]];
    sx = __fadd_rn(sx, pp.x);
    sy = __fadd_rn(sy, pp.y);
    sz = __fadd_rn(sz, pp.z);
  }
  const float k1 = 1.0f / KK;   // exact power of two
  const float mx = sx * k1, my = sy * k1, mz = sz * k1;

  // covariance: plain fp32 mul-then-add (no fma), sequential k order
  float cxx = 0.f, cxy = 0.f, cxz = 0.f, cyy = 0.f, cyz = 0.f, czz = 0.f;
#pragma unroll
  for (int s = 0; s < KK; ++s) {
    float4 pp = Cb[mj[s]];
    float dx = __fsub_rn(pp.x, mx);
    float dy = __fsub_rn(pp.y, my);
    float dz = __fsub_rn(pp.z, mz);
    cxx = __fadd_rn(cxx, __fmul_rn(dx, dx));
    cxy = __fadd_rn(cxy, __fmul_rn(dx, dy));
    cxz = __fadd_rn(cxz, __fmul_rn(dx, dz));
    cyy = __fadd_rn(cyy, __fmul_rn(dy, dy));
    cyz = __fadd_rn(cyz, __fmul_rn(dy, dz));
    czz = __fadd_rn(czz, __fmul_rn(dz, dz));
  }

  // closed-form symmetric 3x3 eigenvalues in double (exact wrt fp32 cov)
  double a   = (double)__fmul_rn(cxx, k1), b = (double)__fmul_rn(cyy, k1);
  double c2  = (double)__fmul_rn(czz, k1);
  double dxy = (double)__fmul_rn(cxy, k1), exz = (double)__fmul_rn(cxz, k1);
  double fyz = (double)__fmul_rn(cyz, k1);
  double qm = (a + b + c2) / 3.0;
  double p1 = dxy * dxy + exz * exz + fyz * fyz;
  double aa = a - qm, bb = b - qm, cc = c2 - qm;
  double p2 = aa * aa + bb * bb + cc * cc + 2.0 * p1;
  double ratio;
  if (p2 <= 0.0) {
    ratio = 1.0;
  } else {
    double p  = sqrt(p2 / 6.0);
    double ip = 1.0 / p;
    double b00 = aa * ip, b11 = bb * ip, b22 = cc * ip;
    double b01 = dxy * ip, b02 = exz * ip, b12 = fyz * ip;
    double detB = b00 * (b11 * b22 - b12 * b12)
                - b01 * (b01 * b22 - b12 * b02)
                + b02 * (b01 * b12 - b11 * b02);
    double r = 0.5 * detB;
    r = fmin(1.0, fmax(-1.0, r));
    double phi = acos(r) / 3.0;
    double e0 = qm + 2.0 * p * cos(phi);                      // largest
    double e2 = qm + 2.0 * p * cos(phi + 2.0943951023931954); // smallest
    double e1 = 3.0 * qm - e0 - e2;                           // middle
    ratio = e0 / e1;
  }
  out[g] = (float)ratio;
}

// ---------------- fallback: verbatim R4 single kernel (proven pass) ---------
__global__ __launch_bounds__(512, 4) void knn_eigen_fallback(
    const float4* __restrict__ cand, float* __restrict__ out) {
  __shared__ unsigned short s_j[NWAVE][QPB][18];

  const int tid   = threadIdx.x;
  const int lane  = tid & 63;
  const int w     = __builtin_amdgcn_readfirstlane(tid >> 6);
  const int batch = blockIdx.x >> 7;
  const int qbase = (blockIdx.x & 127) * QPB;
  const int FCH   = NP / NWAVE;   // 1024

  const float4* __restrict__ Cb = cand + (size_t)batch * NP;

  const float4 q = Cb[qbase + lane];
  const float qx = q.x, qy = q.y, qz = q.z, sqq = q.w;

  float bd[KK];
#pragma unroll
  for (int t = 0; t < KK; ++t) bd[t] = 3.4e38f;

  const int j0 = w * FCH;
  for (int jj = 0; jj < FCH; jj += 8) {
    const float4* xp = Cb + (j0 + jj);
    float4 c[8];
#pragma unroll
    for (int u = 0; u < 8; ++u) c[u] = xp[u];
    float d[8];
#pragma unroll
    for (int u = 0; u < 8; ++u) d[u] = ref_d2q(qx, qy, qz, sqq, c[u]);
    CSWAP_DESC(d[0], d[1]) CSWAP_DESC(d[2], d[3]) CSWAP_DESC(d[4], d[5]) CSWAP_DESC(d[6], d[7])
    CSWAP_DESC(d[0], d[2]) CSWAP_DESC(d[1], d[3]) CSWAP_DESC(d[4], d[6]) CSWAP_DESC(d[5], d[7])
    CSWAP_DESC(d[1], d[2]) CSWAP_DESC(d[5], d[6])
    CSWAP_DESC(d[0], d[4]) CSWAP_DESC(d[1], d[5]) CSWAP_DESC(d[2], d[6]) CSWAP_DESC(d[3], d[7])
    CSWAP_DESC(d[2], d[4]) CSWAP_DESC(d[3], d[5])
    CSWAP_DESC(d[1], d[2]) CSWAP_DESC(d[3], d[4]) CSWAP_DESC(d[5], d[6])
#pragma unroll
    for (int i = 0; i < 8; ++i) bd[8 + i] = fminf(bd[8 + i], d[i]);
#pragma unroll
    for (int i = 0; i < 8; ++i)  CSWAP_ASC(bd[i], bd[i + 8])
#pragma unroll
    for (int i = 0; i < 4; ++i)  CSWAP_ASC(bd[i], bd[i + 4])
#pragma unroll
    for (int i = 8; i < 12; ++i) CSWAP_ASC(bd[i], bd[i + 4])
#pragma unroll
    for (int g = 0; g < 4; ++g) {
      CSWAP_ASC(bd[4 * g + 0], bd[4 * g + 2]) CSWAP_ASC(bd[4 * g + 1], bd[4 * g + 3])
      CSWAP_ASC(bd[4 * g + 0], bd[4 * g + 1]) CSWAP_ASC(bd[4 * g + 2], bd[4 * g + 3])
    }
  }

  const float T = bd[KK - 1];
  int cnt = 0;
  for (int jj = 0; jj < FCH; jj += 8) {
    const float4* xp = Cb + (j0 + jj);
    float4 c[8];
#pragma unroll
    for (int u = 0; u < 8; ++u) c[u] = xp[u];
#pragma unroll
    for (int u = 0; u < 8; ++u) {
      float d = ref_d2q(qx, qy, qz, sqq, c[u]);
      if (d <= T && cnt < KK) {
        s_j[w][lane][cnt] = (unsigned short)(j0 + jj + u);
        cnt++;
      }
    }
  }
  __syncthreads();

  if (tid < QPB) {
    const float4 qq = Cb[qbase + tid];
    const float q2x = qq.x, q2y = qq.y, q2z = qq.z, sq2 = qq.w;
    float md[KK]; int mj[KK];
#pragma unroll
    for (int t = 0; t < KK; ++t) { md[t] = 3.4e38f; mj[t] = 0; }
    for (int cch = 0; cch < NWAVE; ++cch) {
      const unsigned int* rowp = (const unsigned int*)&s_j[cch][tid][0];
#pragma unroll
      for (int sp = 0; sp < KK / 2; ++sp) {
        unsigned int pk = rowp[sp];
#pragma unroll
        for (int half = 0; half < 2; ++half) {
          int j = (half == 0) ? (int)(pk & 0xFFFFu) : (int)(pk >> 16);
          float d = ref_d2q(q2x, q2y, q2z, sq2, Cb[j]);
          if (d < md[KK - 1]) {
            bool c0 = d < md[0];
#pragma unroll
            for (int t = KK - 1; t >= 1; --t) {
              bool cl = d < md[t];
              bool cp = d < md[t - 1];
              float nv = fmaxf(md[t - 1], fminf(md[t], d));
              mj[t] = cl ? (cp ? mj[t - 1] : j) : mj[t];
              md[t] = nv;
            }
            mj[0] = c0 ? j : mj[0];
            md[0] = fminf(md[0], d);
          }
        }
      }
    }
    float sx = 0.f, sy = 0.f, sz = 0.f;
#pragma unroll
    for (int s = 0; s < KK; ++s) {
      float4 pp = Cb[mj[s]];
      sx = __fadd_rn(sx, pp.x);
      sy = __fadd_rn(sy, pp.y);
      sz = __fadd_rn(sz, pp.z);
    }
    const float k1 = 1.0f / KK;
    const float mx = sx * k1, my = sy * k1, mz = sz * k1;
    float cxx = 0.f, cxy = 0.f, cxz = 0.f, cyy = 0.f, cyz = 0.f, czz = 0.f;
#pragma unroll
    for (int s = 0; s < KK; ++s) {
      float4 pp = Cb[mj[s]];
      float dx = __fsub_rn(pp.x, mx);
      float dy = __fsub_rn(pp.y, my);
      float dz = __fsub_rn(pp.z, mz);
      cxx = __fadd_rn(cxx, __fmul_rn(dx, dx));
      cxy = __fadd_rn(cxy, __fmul_rn(dx, dy));
      cxz = __fadd_rn(cxz, __fmul_rn(dx, dz));
      cyy = __fadd_rn(cyy, __fmul_rn(dy, dy));
      cyz = __fadd_rn(cyz, __fmul_rn(dy, dz));
      czz = __fadd_rn(czz, __fmul_rn(dz, dz));
    }
    double a   = (double)__fmul_rn(cxx, k1), b = (double)__fmul_rn(cyy, k1);
    double c2  = (double)__fmul_rn(czz, k1);
    double dxy = (double)__fmul_rn(cxy, k1), exz = (double)__fmul_rn(cxz, k1);
    double fyz = (double)__fmul_rn(cyz, k1);
    double qm = (a + b + c2) / 3.0;
    double p1 = dxy * dxy + exz * exz + fyz * fyz;
    double aa = a - qm, bb = b - qm, cc = c2 - qm;
    double p2 = aa * aa + bb * bb + cc * cc + 2.0 * p1;
    double ratio;
    if (p2 <= 0.0) {
      ratio = 1.0;
    } else {
      double p  = sqrt(p2 / 6.0);
      double ip = 1.0 / p;
      double b00 = aa * ip, b11 = bb * ip, b22 = cc * ip;
      double b01 = dxy * ip, b02 = exz * ip, b12 = fyz * ip;
      double detB = b00 * (b11 * b22 - b12 * b12)
                  - b01 * (b01 * b22 - b12 * b02)
                  + b02 * (b01 * b12 - b11 * b02);
      double r = 0.5 * detB;
      r = fmin(1.0, fmax(-1.0, r));
      double phi = acos(r) / 3.0;
      double e0 = qm + 2.0 * p * cos(phi);
      double e2 = qm + 2.0 * p * cos(phi + 2.0943951023931954);
      double e1 = 3.0 * qm - e0 - e2;
      ratio = e0 / e1;
    }
    out[(size_t)batch * NP + qbase + tid] = (float)ratio;
  }
}

extern "C" void kernel_launch(void* const* d_in, const int* in_sizes, int n_in,
                              void* d_out, int out_size, void* d_ws, size_t ws_size,
                              hipStream_t stream) {
  const float* x = (const float*)d_in[0];
  float* out = (float*)d_out;
  float4* cand = (float4*)d_ws;                               // 512 KB
  unsigned short* lists =
      (unsigned short*)((char*)d_ws + (size_t)NPTS * sizeof(float4));
  const size_t need = (size_t)NPTS * sizeof(float4) +
                      (size_t)NPTS * NCHUNK * KK * sizeof(unsigned short); // ~16.8 MB

  prep_kernel<<<dim3(NPTS / 256), dim3(256), 0, stream>>>(x, cand);
  if (ws_size >= need) {
    knn_lists_kernel<<<dim3(NB * 256), dim3(512), 0, stream>>>(cand, lists);
    merge_eigen_kernel<<<dim3(NPTS / 64), dim3(64), 0, stream>>>(cand, lists, out);
  } else {
    knn_eigen_fallback<<<dim3(NPTS / QPB), dim3(512), 0, stream>>>(cand, out);
  }
}

// Round 8
// 295.439 us; speedup vs baseline: 1.5792x; 1.5792x over previous
//
#include <hip/hip_runtime.h>
#include <math.h>

#define NB 4
#define NP 8192
#define KK 16
#define QPB 64
#define NWAVE 8
#define NCHUNK 16
#define CHUNK (NP / NCHUNK)   // 512
#define NPTS (NB * NP)

// comparator macros (exact: min/max introduce no rounding)
#define CSWAP_DESC(a, b) { float _lo = fminf(a, b); float _hi = fmaxf(a, b); a = _hi; b = _lo; }
#define CSWAP_ASC(a, b)  { float _lo = fminf(a, b); float _hi = fmaxf(a, b); a = _lo; b = _hi; }

// reference-rounded |p|^2 : (xx+yy)+zz
__device__ __forceinline__ float ref_sq(float x, float y, float z) {
  return __fadd_rn(__fadd_rn(__fmul_rn(x, x), __fmul_rn(y, y)), __fmul_rn(z, z));
}

// reference-rounded d2 = (sqq + sqc) - 2*dot, dot = (xx+yy)+zz
__device__ __forceinline__ float ref_d2q(float qx, float qy, float qz, float sqq,
                                         float4 c) {
  float dot = __fadd_rn(__fadd_rn(__fmul_rn(qx, c.x), __fmul_rn(qy, c.y)),
                        __fmul_rn(qz, c.z));
  float s = __fadd_rn(sqq, c.w);
  return __fmaf_rn(-2.0f, dot, s);   // 2*dot exact => identical to fl(s - 2*dot)
}

// batched top-16 update: 8 new distances d[0..7] vs sorted-asc bd[0..15]
__device__ __forceinline__ void topk_update(float bd[KK], float d[8]) {
  // Batcher odd-even mergesort-8, DESCENDING (19 comparators)
  CSWAP_DESC(d[0], d[1]) CSWAP_DESC(d[2], d[3]) CSWAP_DESC(d[4], d[5]) CSWAP_DESC(d[6], d[7])
  CSWAP_DESC(d[0], d[2]) CSWAP_DESC(d[1], d[3]) CSWAP_DESC(d[4], d[6]) CSWAP_DESC(d[5], d[7])
  CSWAP_DESC(d[1], d[2]) CSWAP_DESC(d[5], d[6])
  CSWAP_DESC(d[0], d[4]) CSWAP_DESC(d[1], d[5]) CSWAP_DESC(d[2], d[6]) CSWAP_DESC(d[3], d[7])
  CSWAP_DESC(d[2], d[4]) CSWAP_DESC(d[3], d[5])
  CSWAP_DESC(d[1], d[2]) CSWAP_DESC(d[3], d[4]) CSWAP_DESC(d[5], d[6])

  // [bd_asc(16), +inf x8, d_desc(8)] is bitonic; halver keeps 16 smallest
#pragma unroll
  for (int i = 0; i < 8; ++i) bd[8 + i] = fminf(bd[8 + i], d[i]);

  // bitonic merge-16 ascending cleanup (32 comparators)
#pragma unroll
  for (int i = 0; i < 8; ++i)  CSWAP_ASC(bd[i], bd[i + 8])
#pragma unroll
  for (int i = 0; i < 4; ++i)  CSWAP_ASC(bd[i], bd[i + 4])
#pragma unroll
  for (int i = 8; i < 12; ++i) CSWAP_ASC(bd[i], bd[i + 4])
#pragma unroll
  for (int g = 0; g < 4; ++g) {
    CSWAP_ASC(bd[4 * g + 0], bd[4 * g + 2]) CSWAP_ASC(bd[4 * g + 1], bd[4 * g + 3])
    CSWAP_ASC(bd[4 * g + 0], bd[4 * g + 1]) CSWAP_ASC(bd[4 * g + 2], bd[4 * g + 3])
  }
}

__global__ void prep_kernel(const float* __restrict__ x,
                            float4* __restrict__ cand) {
  int i = blockIdx.x * 256 + threadIdx.x;
  if (i < NPTS) {
    float px = x[3 * i + 0], py = x[3 * i + 1], pz = x[3 * i + 2];
    cand[i] = make_float4(px, py, pz, ref_sq(px, py, pz));
  }
}

// ---------------- k1: per-chunk exact top-16, lists to global ----------------
// VERBATIM from R7-passing kernel.
__global__ __launch_bounds__(512) void knn_lists_kernel(
    const float4* __restrict__ cand, unsigned short* __restrict__ lists) {
  const int tid   = threadIdx.x;
  const int lane  = tid & 63;
  const int w     = __builtin_amdgcn_readfirstlane(tid >> 6);
  const int bid   = blockIdx.x;
  const int batch = bid >> 8;              // 256 blocks per batch
  const int rem   = bid & 255;
  const int group = rem >> 1;
  const int half  = rem & 1;
  const int qbase = group * QPB;
  const int chunkid = half * NWAVE + w;    // 0..15
  const int j0 = chunkid * CHUNK;

  const float4* __restrict__ Cb = cand + (size_t)batch * NP;

  const float4 q = Cb[qbase + lane];
  const float qx = q.x, qy = q.y, qz = q.z, sqq = q.w;

  float bd[KK];
#pragma unroll
  for (int t = 0; t < KK; ++t) bd[t] = 3.4e38f;

  for (int jj = 0; jj < CHUNK; jj += 8) {
    const float4* xp = Cb + (j0 + jj);          // wave-uniform address
    float4 c[8];
#pragma unroll
    for (int u = 0; u < 8; ++u) c[u] = xp[u];

    float d[8];
#pragma unroll
    for (int u = 0; u < 8; ++u) d[u] = ref_d2q(qx, qy, qz, sqq, c[u]);

    CSWAP_DESC(d[0], d[1]) CSWAP_DESC(d[2], d[3]) CSWAP_DESC(d[4], d[5]) CSWAP_DESC(d[6], d[7])
    CSWAP_DESC(d[0], d[2]) CSWAP_DESC(d[1], d[3]) CSWAP_DESC(d[4], d[6]) CSWAP_DESC(d[5], d[7])
    CSWAP_DESC(d[1], d[2]) CSWAP_DESC(d[5], d[6])
    CSWAP_DESC(d[0], d[4]) CSWAP_DESC(d[1], d[5]) CSWAP_DESC(d[2], d[6]) CSWAP_DESC(d[3], d[7])
    CSWAP_DESC(d[2], d[4]) CSWAP_DESC(d[3], d[5])
    CSWAP_DESC(d[1], d[2]) CSWAP_DESC(d[3], d[4]) CSWAP_DESC(d[5], d[6])

#pragma unroll
    for (int i = 0; i < 8; ++i) bd[8 + i] = fminf(bd[8 + i], d[i]);

#pragma unroll
    for (int i = 0; i < 8; ++i)  CSWAP_ASC(bd[i], bd[i + 8])
#pragma unroll
    for (int i = 0; i < 4; ++i)  CSWAP_ASC(bd[i], bd[i + 4])
#pragma unroll
    for (int i = 8; i < 12; ++i) CSWAP_ASC(bd[i], bd[i + 4])
#pragma unroll
    for (int g = 0; g < 4; ++g) {
      CSWAP_ASC(bd[4 * g + 0], bd[4 * g + 2]) CSWAP_ASC(bd[4 * g + 1], bd[4 * g + 3])
      CSWAP_ASC(bd[4 * g + 0], bd[4 * g + 1]) CSWAP_ASC(bd[4 * g + 2], bd[4 * g + 3])
    }
  }

  const float T = bd[KK - 1];   // exact 16th-smallest (ref-rounded) in chunk

  unsigned short* Lrow =
      lists + (((size_t)batch * NP + qbase + lane) * NCHUNK + chunkid) * KK;
  int cnt = 0;
  for (int jj = 0; jj < CHUNK; jj += 8) {
    const float4* xp = Cb + (j0 + jj);
    float4 c[8];
#pragma unroll
    for (int u = 0; u < 8; ++u) c[u] = xp[u];
#pragma unroll
    for (int u = 0; u < 8; ++u) {
      float d = ref_d2q(qx, qy, qz, sqq, c[u]);
      if (d <= T && cnt < KK) {
        Lrow[cnt] = (unsigned short)(j0 + jj + u);
        cnt++;
      }
    }
  }
}

// ---------------- k2: merge 16 lists + covariance + eigen (REWRITTEN) -------
// grid: 512 blocks x 64 threads; one query per thread.
// Pass 1: gather-up-front per list, batched network for exact global T,
//         distances cached in a private LDS column (bitwise round-trip).
// Pass 2: ascending-global-index threshold append (chunks partition in order).
__global__ __launch_bounds__(64) void merge_eigen_kernel(
    const float4* __restrict__ cand, const unsigned short* __restrict__ lists,
    float* __restrict__ out) {
  __shared__ float s_d[NCHUNK * KK][64];         // 64 KB: d-cache, [cand][lane]
  __shared__ unsigned short s_mj[64][KK];        // 2 KB: selected indices

  const int tid = threadIdx.x;
  const int g = blockIdx.x * 64 + tid;           // global query id
  const int batch = g >> 13;                     // / NP
  const float4* __restrict__ Cb = cand + (size_t)batch * NP;

  const float4 qq = cand[g];
  const float q2x = qq.x, q2y = qq.y, q2z = qq.z, sq2 = qq.w;

  const unsigned int* Lq = (const unsigned int*)(lists + (size_t)g * NCHUNK * KK);

  // ---- pass 1: exact global 16th-smallest over the 256-candidate union
  float bd[KK];
#pragma unroll
  for (int t = 0; t < KK; ++t) bd[t] = 3.4e38f;

  for (int cch = 0; cch < NCHUNK; ++cch) {
    unsigned int pks[KK / 2];
#pragma unroll
    for (int sp = 0; sp < KK / 2; ++sp) pks[sp] = Lq[cch * (KK / 2) + sp];
    int jidx[KK];
#pragma unroll
    for (int sp = 0; sp < KK / 2; ++sp) {
      jidx[2 * sp]     = (int)(pks[sp] & 0xFFFFu);
      jidx[2 * sp + 1] = (int)(pks[sp] >> 16);
    }
    float4 gp[KK];
#pragma unroll
    for (int e = 0; e < KK; ++e) gp[e] = Cb[jidx[e]];   // all 16 gathers in flight
    float d[KK];
#pragma unroll
    for (int e = 0; e < KK; ++e) d[e] = ref_d2q(q2x, q2y, q2z, sq2, gp[e]);
#pragma unroll
    for (int e = 0; e < KK; ++e) s_d[cch * KK + e][tid] = d[e];  // cache (bitwise)
    topk_update(bd, &d[0]);
    topk_update(bd, &d[8]);
  }

  const float T = bd[KK - 1];   // exact global 16th-smallest

  // ---- pass 2: threshold append in ascending global-index order
  int cnt = 0;
  for (int cch = 0; cch < NCHUNK; ++cch) {
#pragma unroll
    for (int sp = 0; sp < KK / 2; ++sp) {
      unsigned int pk = Lq[cch * (KK / 2) + sp];
#pragma unroll
      for (int half = 0; half < 2; ++half) {
        int j = (half == 0) ? (int)(pk & 0xFFFFu) : (int)(pk >> 16);
        float d = s_d[cch * KK + sp * 2 + half][tid];
        if (d <= T && cnt < KK) {
          s_mj[tid][cnt] = (unsigned short)j;
          cnt++;
        }
      }
    }
  }

  // ---- covariance + eigen tail (verbatim-verified arithmetic)
  int mj[KK];
#pragma unroll
  for (int s = 0; s < KK; ++s) mj[s] = s_mj[tid][s];

  float sx = 0.f, sy = 0.f, sz = 0.f;
#pragma unroll
  for (int s = 0; s < KK; ++s) {
    float4 pp = Cb[mj[s]];
    sx = __fadd_rn(sx, pp.x);
    sy = __fadd_rn(sy, pp.y);
    sz = __fadd_rn(sz, pp.z);
  }
  const float k1 = 1.0f / KK;   // exact power of two
  const float mx = sx * k1, my = sy * k1, mz = sz * k1;

  float cxx = 0.f, cxy = 0.f, cxz = 0.f, cyy = 0.f, cyz = 0.f, czz = 0.f;
#pragma unroll
  for (int s = 0; s < KK; ++s) {
    float4 pp = Cb[mj[s]];
    float dx = __fsub_rn(pp.x, mx);
    float dy = __fsub_rn(pp.y, my);
    float dz = __fsub_rn(pp.z, mz);
    cxx = __fadd_rn(cxx, __fmul_rn(dx, dx));
    cxy = __fadd_rn(cxy, __fmul_rn(dx, dy));
    cxz = __fadd_rn(cxz, __fmul_rn(dx, dz));
    cyy = __fadd_rn(cyy, __fmul_rn(dy, dy));
    cyz = __fadd_rn(cyz, __fmul_rn(dy, dz));
    czz = __fadd_rn(czz, __fmul_rn(dz, dz));
  }

  double a   = (double)__fmul_rn(cxx, k1), b = (double)__fmul_rn(cyy, k1);
  double c2  = (double)__fmul_rn(czz, k1);
  double dxy = (double)__fmul_rn(cxy, k1), exz = (double)__fmul_rn(cxz, k1);
  double fyz = (double)__fmul_rn(cyz, k1);
  double qm = (a + b + c2) / 3.0;
  double p1 = dxy * dxy + exz * exz + fyz * fyz;
  double aa = a - qm, bb = b - qm, cc = c2 - qm;
  double p2 = aa * aa + bb * bb + cc * cc + 2.0 * p1;
  double ratio;
  if (p2 <= 0.0) {
    ratio = 1.0;
  } else {
    double p  = sqrt(p2 / 6.0);
    double ip = 1.0 / p;
    double b00 = aa * ip, b11 = bb * ip, b22 = cc * ip;
    double b01 = dxy * ip, b02 = exz * ip, b12 = fyz * ip;
    double detB = b00 * (b11 * b22 - b12 * b12)
                - b01 * (b01 * b22 - b12 * b02)
                + b02 * (b01 * b12 - b11 * b02);
    double r = 0.5 * detB;
    r = fmin(1.0, fmax(-1.0, r));
    double phi = acos(r) / 3.0;
    double e0 = qm + 2.0 * p * cos(phi);                      // largest
    double e2 = qm + 2.0 * p * cos(phi + 2.0943951023931954); // smallest
    double e1 = 3.0 * qm - e0 - e2;                           // middle
    ratio = e0 / e1;
  }
  out[g] = (float)ratio;
}

// ---------------- fallback: verbatim R4 single kernel (proven pass) ---------
__global__ __launch_bounds__(512, 4) void knn_eigen_fallback(
    const float4* __restrict__ cand, float* __restrict__ out) {
  __shared__ unsigned short s_j[NWAVE][QPB][18];

  const int tid   = threadIdx.x;
  const int lane  = tid & 63;
  const int w     = __builtin_amdgcn_readfirstlane(tid >> 6);
  const int batch = blockIdx.x >> 7;
  const int qbase = (blockIdx.x & 127) * QPB;
  const int FCH   = NP / NWAVE;   // 1024

  const float4* __restrict__ Cb = cand + (size_t)batch * NP;

  const float4 q = Cb[qbase + lane];
  const float qx = q.x, qy = q.y, qz = q.z, sqq = q.w;

  float bd[KK];
#pragma unroll
  for (int t = 0; t < KK; ++t) bd[t] = 3.4e38f;

  const int j0 = w * FCH;
  for (int jj = 0; jj < FCH; jj += 8) {
    const float4* xp = Cb + (j0 + jj);
    float4 c[8];
#pragma unroll
    for (int u = 0; u < 8; ++u) c[u] = xp[u];
    float d[8];
#pragma unroll
    for (int u = 0; u < 8; ++u) d[u] = ref_d2q(qx, qy, qz, sqq, c[u]);
    CSWAP_DESC(d[0], d[1]) CSWAP_DESC(d[2], d[3]) CSWAP_DESC(d[4], d[5]) CSWAP_DESC(d[6], d[7])
    CSWAP_DESC(d[0], d[2]) CSWAP_DESC(d[1], d[3]) CSWAP_DESC(d[4], d[6]) CSWAP_DESC(d[5], d[7])
    CSWAP_DESC(d[1], d[2]) CSWAP_DESC(d[5], d[6])
    CSWAP_DESC(d[0], d[4]) CSWAP_DESC(d[1], d[5]) CSWAP_DESC(d[2], d[6]) CSWAP_DESC(d[3], d[7])
    CSWAP_DESC(d[2], d[4]) CSWAP_DESC(d[3], d[5])
    CSWAP_DESC(d[1], d[2]) CSWAP_DESC(d[3], d[4]) CSWAP_DESC(d[5], d[6])
#pragma unroll
    for (int i = 0; i < 8; ++i) bd[8 + i] = fminf(bd[8 + i], d[i]);
#pragma unroll
    for (int i = 0; i < 8; ++i)  CSWAP_ASC(bd[i], bd[i + 8])
#pragma unroll
    for (int i = 0; i < 4; ++i)  CSWAP_ASC(bd[i], bd[i + 4])
#pragma unroll
    for (int i = 8; i < 12; ++i) CSWAP_ASC(bd[i], bd[i + 4])
#pragma unroll
    for (int g = 0; g < 4; ++g) {
      CSWAP_ASC(bd[4 * g + 0], bd[4 * g + 2]) CSWAP_ASC(bd[4 * g + 1], bd[4 * g + 3])
      CSWAP_ASC(bd[4 * g + 0], bd[4 * g + 1]) CSWAP_ASC(bd[4 * g + 2], bd[4 * g + 3])
    }
  }

  const float T = bd[KK - 1];
  int cnt = 0;
  for (int jj = 0; jj < FCH; jj += 8) {
    const float4* xp = Cb + (j0 + jj);
    float4 c[8];
#pragma unroll
    for (int u = 0; u < 8; ++u) c[u] = xp[u];
#pragma unroll
    for (int u = 0; u < 8; ++u) {
      float d = ref_d2q(qx, qy, qz, sqq, c[u]);
      if (d <= T && cnt < KK) {
        s_j[w][lane][cnt] = (unsigned short)(j0 + jj + u);
        cnt++;
      }
    }
  }
  __syncthreads();

  if (tid < QPB) {
    const float4 qq = Cb[qbase + tid];
    const float q2x = qq.x, q2y = qq.y, q2z = qq.z, sq2 = qq.w;
    float md[KK]; int mj[KK];
#pragma unroll
    for (int t = 0; t < KK; ++t) { md[t] = 3.4e38f; mj[t] = 0; }
    for (int cch = 0; cch < NWAVE; ++cch) {
      const unsigned int* rowp = (const unsigned int*)&s_j[cch][tid][0];
#pragma unroll
      for (int sp = 0; sp < KK / 2; ++sp) {
        unsigned int pk = rowp[sp];
#pragma unroll
        for (int half = 0; half < 2; ++half) {
          int j = (half == 0) ? (int)(pk & 0xFFFFu) : (int)(pk >> 16);
          float d = ref_d2q(q2x, q2y, q2z, sq2, Cb[j]);
          if (d < md[KK - 1]) {
            bool c0 = d < md[0];
#pragma unroll
            for (int t = KK - 1; t >= 1; --t) {
              bool cl = d < md[t];
              bool cp = d < md[t - 1];
              float nv = fmaxf(md[t - 1], fminf(md[t], d));
              mj[t] = cl ? (cp ? mj[t - 1] : j) : mj[t];
              md[t] = nv;
            }
            mj[0] = c0 ? j : mj[0];
            md[0] = fminf(md[0], d);
          }
        }
      }
    }
    float sx = 0.f, sy = 0.f, sz = 0.f;
#pragma unroll
    for (int s = 0; s < KK; ++s) {
      float4 pp = Cb[mj[s]];
      sx = __fadd_rn(sx, pp.x);
      sy = __fadd_rn(sy, pp.y);
      sz = __fadd_rn(sz, pp.z);
    }
    const float k1 = 1.0f / KK;
    const float mx = sx * k1, my = sy * k1, mz = sz * k1;
    float cxx = 0.f, cxy = 0.f, cxz = 0.f, cyy = 0.f, cyz = 0.f, czz = 0.f;
#pragma unroll
    for (int s = 0; s < KK; ++s) {
      float4 pp = Cb[mj[s]];
      float dx = __fsub_rn(pp.x, mx);
      float dy = __fsub_rn(pp.y, my);
      float dz = __fsub_rn(pp.z, mz);
      cxx = __fadd_rn(cxx, __fmul_rn(dx, dx));
      cxy = __fadd_rn(cxy, __fmul_rn(dx, dy));
      cxz = __fadd_rn(cxz, __fmul_rn(dx, dz));
      cyy = __fadd_rn(cyy, __fmul_rn(dy, dy));
      cyz = __fadd_rn(cyz, __fmul_rn(dy, dz));
      czz = __fadd_rn(czz, __fmul_rn(dz, dz));
    }
    double a   = (double)__fmul_rn(cxx, k1), b = (double)__fmul_rn(cyy, k1);
    double c2  = (double)__fmul_rn(czz, k1);
    double dxy = (double)__fmul_rn(cxy, k1), exz = (double)__fmul_rn(cxz, k1);
    double fyz = (double)__fmul_rn(cyz, k1);
    double qm = (a + b + c2) / 3.0;
    double p1 = dxy * dxy + exz * exz + fyz * fyz;
    double aa = a - qm, bb = b - qm, cc = c2 - qm;
    double p2 = aa * aa + bb * bb + cc * cc + 2.0 * p1;
    double ratio;
    if (p2 <= 0.0) {
      ratio = 1.0;
    } else {
      double p  = sqrt(p2 / 6.0);
      double ip = 1.0 / p;
      double b00 = aa * ip, b11 = bb * ip, b22 = cc * ip;
      double b01 = dxy * ip, b02 = exz * ip, b12 = fyz * ip;
      double detB = b00 * (b11 * b22 - b12 * b12)
                  - b01 * (b01 * b22 - b12 * b02)
                  + b02 * (b01 * b12 - b11 * b02);
      double r = 0.5 * detB;
      r = fmin(1.0, fmax(-1.0, r));
      double phi = acos(r) / 3.0;
      double e0 = qm + 2.0 * p * cos(phi);
      double e2 = qm + 2.0 * p * cos(phi + 2.0943951023931954);
      double e1 = 3.0 * qm - e0 - e2;
      ratio = e0 / e1;
    }
    out[(size_t)batch * NP + qbase + tid] = (float)ratio;
  }
}

extern "C" void kernel_launch(void* const* d_in, const int* in_sizes, int n_in,
                              void* d_out, int out_size, void* d_ws, size_t ws_size,
                              hipStream_t stream) {
  const float* x = (const float*)d_in[0];
  float* out = (float*)d_out;
  float4* cand = (float4*)d_ws;                               // 512 KB
  unsigned short* lists =
      (unsigned short*)((char*)d_ws + (size_t)NPTS * sizeof(float4));
  const size_t need = (size_t)NPTS * sizeof(float4) +
                      (size_t)NPTS * NCHUNK * KK * sizeof(unsigned short); // ~16.8 MB

  prep_kernel<<<dim3(NPTS / 256), dim3(256), 0, stream>>>(x, cand);
  if (ws_size >= need) {
    knn_lists_kernel<<<dim3(NB * 256), dim3(512), 0, stream>>>(cand, lists);
    merge_eigen_kernel<<<dim3(NPTS / 64), dim3(64), 0, stream>>>(cand, lists, out);
  } else {
    knn_eigen_fallback<<<dim3(NPTS / QPB), dim3(512), 0, stream>>>(cand, out);
  }
}